// Round 1
// baseline (229.085 us; speedup 1.0000x reference)
//
#include <hip/hip_runtime.h>

#define NEI 16
#define KK 4
#define DIN 64
#define DOUT 64
#define WAVES 8
#define BLK (WAVES * 64)

__device__ __forceinline__ float wave_bcast_sum(float v) {
#pragma unroll
  for (int s = 1; s < 64; s <<= 1) v += __shfl_xor(v, s, 64);
  return v;
}

__device__ __forceinline__ float artanh_c(float z) {
  z = fminf(z, 1.0f - 1e-7f);
  z = fmaxf(z, -1.0f + 1e-7f);
  return atanhf(z);
}

// Prologue: per point j, precompute Q[j] = |x_j|^2 and P[j][k] = x_j . x_kernel[k]
__global__ __launch_bounds__(BLK) void kpa_pre(const float* __restrict__ x,
                                               const float* __restrict__ kt,
                                               float4* __restrict__ P,
                                               float* __restrict__ Q,
                                               int npts) {
  __shared__ float sXK[KK][DIN];
  const int tid = threadIdx.x, wv = tid >> 6, lane = tid & 63;
  if (wv < KK) {
    float v = kt[wv * DIN + lane];
    float n2 = wave_bcast_sum(v * v);
    float nr = sqrtf(fmaxf(n2, 1e-14f));
    sXK[wv][lane] = tanhf(nr) / nr * v;  // x_kernel = expmap0(kt)
  }
  __syncthreads();
  const int b = blockIdx.x * WAVES + wv;
  if (b >= npts) return;
  const float xb = x[(size_t)b * DIN + lane];
  const float q = wave_bcast_sum(xb * xb);
  float d[KK];
#pragma unroll
  for (int k = 0; k < KK; ++k) d[k] = wave_bcast_sum(xb * sXK[k][lane]);
  if (lane == 0) {
    Q[b] = q;
    P[b] = make_float4(d[0], d[1], d[2], d[3]);
  }
}

__global__ __launch_bounds__(BLK) void kpa_main(
    const float* __restrict__ x, const int* __restrict__ nei,
    const float* __restrict__ nmask, const float* __restrict__ Wg,
    const float* __restrict__ bias, const float* __restrict__ kt,
    const float4* __restrict__ P, const float* __restrict__ Q,
    float* __restrict__ out, int npts, int usePre) {
  __shared__ __align__(16) float sW[KK * DOUT * DIN];      // 64 KB, XOR-swizzled 16B chunks
  __shared__ __align__(16) float sU[WAVES][NEI][DIN];      // 32 KB
  __shared__ float sXK[KK][DIN];
  __shared__ float sEB[KK][DOUT];
  __shared__ float sXK2[KK], sEB2[KK];
  __shared__ float sWgt[WAVES][KK][NEI];
  __shared__ int sAny;

  const int tid = threadIdx.x, wv = tid >> 6, lane = tid & 63;
  if (tid == 0) sAny = 0;

  // stage x_kernel (waves 0..3) and expmap0(bias) (waves 4..7)
  if (wv < KK) {
    float v = kt[wv * DIN + lane];
    float n2 = wave_bcast_sum(v * v);
    float nr = sqrtf(fmaxf(n2, 1e-14f));
    float xkv = tanhf(nr) / nr * v;
    sXK[wv][lane] = xkv;
    float s2 = wave_bcast_sum(xkv * xkv);
    if (lane == 0) sXK2[wv] = s2;
  } else if (wv < 2 * KK) {
    const int k = wv - KK;
    float v = bias[k * DOUT + lane];
    float n2 = wave_bcast_sum(v * v);
    float nr = sqrtf(fmaxf(n2, 1e-14f));
    float ebv = tanhf(nr) / nr * v;
    sEB[k][lane] = ebv;
    float s2 = wave_bcast_sum(ebv * ebv);
    if (lane == 0) sEB2[k] = s2;
  }
  __syncthreads();

  const int b = blockIdx.x * WAVES + wv;
  const bool alive = b < npts;

  unsigned actK[KK] = {0u, 0u, 0u, 0u};

  if (alive) {
    const float xb = x[(size_t)b * DIN + lane];
    float x2, Pb[KK];
    if (usePre) {
      x2 = Q[b];
      float4 p4 = P[b];
      Pb[0] = p4.x; Pb[1] = p4.y; Pb[2] = p4.z; Pb[3] = p4.w;
    } else {
      x2 = wave_bcast_sum(xb * xb);
#pragma unroll
      for (int k = 0; k < KK; ++k) Pb[k] = wave_bcast_sum(xb * sXK[k][lane]);
    }

    int jn = 0; float mkv = 0.f, qj = 0.f;
    float pj0 = 0.f, pj1 = 0.f, pj2 = 0.f, pj3 = 0.f;
    if (lane < NEI) {
      jn = nei[b * NEI + lane];
      mkv = nmask[b * NEI + lane];
      if (usePre) {
        qj = Q[jn];
        float4 p4 = P[jn];
        pj0 = p4.x; pj1 = p4.y; pj2 = p4.z; pj3 = p4.w;
      }
    }

    int ji[NEI];
#pragma unroll
    for (int n = 0; n < NEI; ++n) ji[n] = __shfl(jn, n, 64);
    float yv[NEI];
#pragma unroll
    for (int n = 0; n < NEI; ++n) yv[n] = x[(size_t)ji[n] * DIN + lane];

    // batched cross-lane reductions: 16 independent butterfly chains (ILP)
    float xyv[NEI];
#pragma unroll
    for (int n = 0; n < NEI; ++n) xyv[n] = xb * yv[n];
#pragma unroll
    for (int s = 1; s < 64; s <<= 1) {
#pragma unroll
      for (int n = 0; n < NEI; ++n) xyv[n] += __shfl_xor(xyv[n], s, 64);
    }

    float y2v[NEI];
    if (!usePre) {
#pragma unroll
      for (int n = 0; n < NEI; ++n) y2v[n] = yv[n] * yv[n];
#pragma unroll
      for (int s = 1; s < 64; s <<= 1) {
#pragma unroll
        for (int n = 0; n < NEI; ++n) y2v[n] += __shfl_xor(y2v[n], s, 64);
      }
    }

    const float T2 = 0.101505f;  // tanh(0.33)^2 + margin: active gate for w>0
    const float B = 1.f - x2;

#pragma unroll 1
    for (int n = 0; n < NEI; ++n) {
      const float xy = xyv[n];
      const float msk = __shfl(mkv, n, 64);
      float y2, Pj[KK];
      if (usePre) {
        y2 = __shfl(qj, n, 64);
        Pj[0] = __shfl(pj0, n, 64);
        Pj[1] = __shfl(pj1, n, 64);
        Pj[2] = __shfl(pj2, n, 64);
        Pj[3] = __shfl(pj3, n, 64);
      } else {
        y2 = y2v[n];
      }
      // m = mobius_add(-x, y);  x0 = proj(m)  (== proj(expmap0(ptransp0back(logmap(..)))))
      const float A = 1.f - 2.f * xy + y2;
      const float den = fmaxf(1.f - 2.f * xy + x2 * y2, 1e-15f);
      const float inv = 1.f / den;
      const float num2 = fmaxf(A * A * x2 - 2.f * A * B * xy + B * B * y2, 0.f);
      const float nm2 = num2 * inv * inv;
      const float nmr = sqrtf(fmaxf(nm2, 1e-14f));
      const float scl = (nmr > 0.99999f) ? (0.99999f / nmr) : 1.f;
      const float fac = inv * scl;
      const float n02 = nm2 * scl * scl;
      const float B2 = 1.f - n02;
      const float x0t = fac * (B * yv[n] - A * xb);

      bool anyact = false;
#pragma unroll
      for (int k = 0; k < KK; ++k) {
        float d;
        if (usePre) d = fac * (B * Pj[k] - A * Pb[k]);
        else d = wave_bcast_sum(x0t * sXK[k][lane]);
        const float xk2 = sXK2[k];
        const float A2 = 1.f - 2.f * d + xk2;
        const float dn2 = fmaxf(1.f - 2.f * d + n02 * xk2, 1e-15f);
        const float nu2 = fmaxf(A2 * A2 * n02 - 2.f * A2 * B2 * d + B2 * B2 * xk2, 0.f);
        const float mm2 = nu2 / (dn2 * dn2);
        float w = 0.f;
        if (mm2 < T2 && msk > 0.f) {
          const float dis = 2.f * artanh_c(sqrtf(fmaxf(mm2, 1e-14f)));
          w = fmaxf(1.f - dis * (1.f / 0.66f), 0.f) * msk;
        }
        if (lane == 0) sWgt[wv][k][n] = w;
        if (w > 0.f) { actK[k] |= (1u << n); anyact = true; }
      }
      if (anyact) {  // u = logmap0(x0), only needed for active neighbors
        const float n0 = sqrtf(fmaxf(n02, 1e-14f));
        const float al = artanh_c(n0) / n0;
        sU[wv][n][lane] = al * x0t;
      }
    }

    if (lane == 0 && (actK[0] | actK[1] | actK[2] | actK[3])) sAny = 1;
  }

  __syncthreads();
  // stage W into LDS (XOR-swizzled 16B chunks) only if any pair in block is active
  if (sAny) {
    const float4* Wv = reinterpret_cast<const float4*>(Wg);
    float4* Ws = reinterpret_cast<float4*>(sW);
#pragma unroll
    for (int it = 0; it < (KK * DOUT * 16) / BLK; ++it) {
      const int c = it * BLK + tid;
      const float4 v = Wv[c];
      const int g = c & 15, ko = c >> 4, o = ko & 63;
      Ws[(ko << 4) + (g ^ (o & 15))] = v;
    }
  }
  __syncthreads();

  if (!alive) return;

  float midv[KK];
  const int sw = lane & 15;
#pragma unroll 1
  for (int k = 0; k < KK; ++k) {
    float macc = 0.f, wsm = 0.f;
    unsigned act = actK[k];
    const float ebt = sEB[k][lane];
    const float eb2 = sEB2[k];
    const float4* wrow = reinterpret_cast<const float4*>(sW) + ((k * DOUT + lane) << 4);
    while (act) {
      const int n = __ffs(act) - 1;
      act &= act - 1;
      const float w = sWgt[wv][k][n];
      const float4* urow = reinterpret_cast<const float4*>(&sU[wv][n][0]);
      // h_pre[o=lane] = sum_d W[k][o][d] * u[n][d]   (swizzled conflict-free b128)
      float a0 = 0.f, a1 = 0.f, a2 = 0.f, a3 = 0.f;
#pragma unroll
      for (int g = 0; g < 16; ++g) {
        const float4 w4 = wrow[g ^ sw];
        const float4 u4 = urow[g];
        a0 = fmaf(w4.x, u4.x, a0);
        a1 = fmaf(w4.y, u4.y, a1);
        a2 = fmaf(w4.z, u4.z, a2);
        a3 = fmaf(w4.w, u4.w, a3);
      }
      const float hpre = (a0 + a1) + (a2 + a3);
      // h = expmap0(h_pre)
      const float nh2 = wave_bcast_sum(hpre * hpre);
      const float nh = sqrtf(fmaxf(nh2, 1e-14f));
      const float sh = tanhf(nh) / nh;
      const float ht = sh * hpre;
      const float hx2 = sh * sh * nh2;
      // proj(mobius_add(h, eb))
      const float hxy = wave_bcast_sum(ht * ebt);
      const float A3 = 1.f + 2.f * hxy + eb2;
      const float B3 = 1.f - hx2;
      const float dn3 = fmaxf(1.f + 2.f * hxy + hx2 * eb2, 1e-15f);
      float hm = (A3 * ht + B3 * ebt) / dn3;
      float n2h = wave_bcast_sum(hm * hm);
      const float nnh = sqrtf(fmaxf(n2h, 1e-14f));
      if (nnh > 0.99999f) {
        const float s = 0.99999f / nnh;
        hm *= s; n2h *= s * s;
      }
      // kx = p2k(hm); gamma(kx)
      const float ip = 1.f / (1.f + n2h);
      const float kx = 2.f * hm * ip;
      const float kx2 = 4.f * n2h * ip * ip;
      const float gam = 1.f / sqrtf(fmaxf(1.f - kx2, 1e-7f));
      const float wgv = w * gam;
      macc = fmaf(wgv, kx, macc);
      wsm += wgv;
    }
    midv[k] = macc / fmaxf(wsm, 1e-10f);
  }

  // out_k = sum_k gamma(mid)*mid / sum_k gamma(mid)
  float m2v[KK];
#pragma unroll
  for (int k = 0; k < KK; ++k) m2v[k] = midv[k] * midv[k];
#pragma unroll
  for (int s = 1; s < 64; s <<= 1) {
#pragma unroll
    for (int k = 0; k < KK; ++k) m2v[k] += __shfl_xor(m2v[k], s, 64);
  }
  float onum = 0.f, oden = 0.f;
#pragma unroll
  for (int k = 0; k < KK; ++k) {
    const float g = 1.f / sqrtf(fmaxf(1.f - m2v[k], 1e-7f));
    onum = fmaf(g, midv[k], onum);
    oden += g;
  }

  const float ok = onum / fmaxf(oden, 1e-10f);
  const float no2 = wave_bcast_sum(ok * ok);
  // proj(k2p(out_k)) then expmap0(relu(logmap0(.)))
  float p = ok / (1.f + sqrtf(fmaxf(1.f - no2, 1e-7f)));
  float np2 = wave_bcast_sum(p * p);
  float npn = sqrtf(fmaxf(np2, 1e-14f));
  if (npn > 0.99999f) {
    p *= 0.99999f / npn;
    npn = 0.99999f;
  }
  const float al = artanh_c(npn) / npn;
  const float r = fmaxf(al * p, 0.f);
  const float nr2 = wave_bcast_sum(r * r);
  const float nr = sqrtf(fmaxf(nr2, 1e-14f));
  out[(size_t)b * DOUT + lane] = tanhf(nr) / nr * r;
}

extern "C" void kernel_launch(void* const* d_in, const int* in_sizes, int n_in,
                              void* d_out, int out_size, void* d_ws, size_t ws_size,
                              hipStream_t stream) {
  const float* x = (const float*)d_in[0];
  const int* nei = (const int*)d_in[1];
  const float* nmask = (const float*)d_in[2];
  const float* W = (const float*)d_in[3];
  const float* bias = (const float*)d_in[4];
  const float* kt = (const float*)d_in[5];
  float* out = (float*)d_out;

  const int npts = in_sizes[0] / DIN;
  const size_t need = (size_t)npts * (KK + 1) * sizeof(float);
  const int usePre = (d_ws != nullptr && ws_size >= need) ? 1 : 0;
  float4* P = (float4*)d_ws;
  float* Q = (float*)((char*)d_ws + (size_t)npts * KK * sizeof(float));

  const int grid = (npts + WAVES - 1) / WAVES;
  if (usePre) kpa_pre<<<grid, BLK, 0, stream>>>(x, kt, P, Q, npts);
  kpa_main<<<grid, BLK, 0, stream>>>(x, nei, nmask, W, bias, kt, P, Q, out, npts, usePre);
}

// Round 2
// 49.078 us; speedup vs baseline: 4.6678x; 4.6678x over previous
//
#include <hip/hip_runtime.h>

#define NEI 16
#define KK 4
#define DIN 64
#define DOUT 64
#define WPB 4
#define BLK (WPB * 64)

__device__ __forceinline__ float wave_bcast_sum(float v) {
#pragma unroll
  for (int s = 1; s < 64; s <<= 1) v += __shfl_xor(v, s, 64);
  return v;
}

__device__ __forceinline__ float artanh_c(float z) {
  z = fminf(z, 1.0f - 1e-7f);
  z = fmaxf(z, -1.0f + 1e-7f);
  return atanhf(z);
}

// Prologue: per point j, Q[j] = |x_j|^2 and P[j][k] = x_j . x_kernel[k]
__global__ __launch_bounds__(BLK) void kpa_pre(const float* __restrict__ x,
                                               const float* __restrict__ kt,
                                               float4* __restrict__ P,
                                               float* __restrict__ Q,
                                               int npts) {
  __shared__ float sXK[KK][DIN];
  const int tid = threadIdx.x, wv = tid >> 6, lane = tid & 63;
  {
    float v = kt[wv * DIN + lane];
    float n2 = wave_bcast_sum(v * v);
    float nr = sqrtf(fmaxf(n2, 1e-14f));
    sXK[wv][lane] = tanhf(nr) / nr * v;  // x_kernel = expmap0(kt)
  }
  __syncthreads();
  const int b = blockIdx.x * WPB + wv;
  if (b >= npts) return;
  const float xb = x[(size_t)b * DIN + lane];
  float r[5];
  r[0] = xb * xb;
  r[1] = xb * sXK[0][lane];
  r[2] = xb * sXK[1][lane];
  r[3] = xb * sXK[2][lane];
  r[4] = xb * sXK[3][lane];
#pragma unroll
  for (int s = 1; s < 64; s <<= 1) {
#pragma unroll
    for (int i = 0; i < 5; ++i) r[i] += __shfl_xor(r[i], s, 64);
  }
  if (lane == 0) {
    Q[b] = r[0];
    P[b] = make_float4(r[1], r[2], r[3], r[4]);
  }
}

// Main: one wave per point. Gate phase: lane = (neighbor n = lane>>2, kernel k = lane&3).
__global__ __launch_bounds__(BLK, 5) void kpa_main2(
    const float* __restrict__ x, const int* __restrict__ nei,
    const float* __restrict__ nmask, const float* __restrict__ Wg,
    const float* __restrict__ bias, const float* __restrict__ kt,
    const float4* __restrict__ P, const float* __restrict__ Q,
    float* __restrict__ out, int npts) {
  __shared__ float sXK[KK][DIN];
  __shared__ float sEB[KK][DOUT];
  __shared__ float sXK2[KK], sEB2[KK];
  __shared__ __align__(16) float sUv[WPB][DIN];

  const int tid = threadIdx.x, wv = tid >> 6, lane = tid & 63;
  // staging: wave wv handles x_kernel[wv] and expmap0(bias[wv])
  {
    float v = kt[wv * DIN + lane];
    float bv = bias[wv * DOUT + lane];
    float n2 = wave_bcast_sum(v * v);
    float nr = sqrtf(fmaxf(n2, 1e-14f));
    float t = tanhf(nr);
    sXK[wv][lane] = t / nr * v;
    float bn2 = wave_bcast_sum(bv * bv);
    float bnr = sqrtf(fmaxf(bn2, 1e-14f));
    float tb = tanhf(bnr);
    sEB[wv][lane] = tb / bnr * bv;
    if (lane == 0) {
      sXK2[wv] = t * t;   // |expmap0(kt)|^2 = tanh(|kt|)^2
      sEB2[wv] = tb * tb;
    }
  }
  __syncthreads();

  const int b = blockIdx.x * WPB + wv;
  if (b >= npts) return;

  const float xb = x[(size_t)b * DIN + lane];
  const float x2 = Q[b];
  const int nn = lane >> 2, kme = lane & 3;
  const int jme = nei[b * NEI + nn];
  const float mskme = nmask[b * NEI + nn];
  const float y2me = Q[jme];
  const float Pjme = ((const float*)P)[(size_t)jme * 4 + kme];
  const float Pbme = ((const float*)P)[(size_t)b * 4 + kme];

  // 16 dots xb . y_n, two batches of 8 butterfly chains (ILP, capped VGPR)
  float xyv[NEI];
#pragma unroll
  for (int h = 0; h < 2; ++h) {
    float yb8[8];
#pragma unroll
    for (int n = 0; n < 8; ++n) {
      const int j = __shfl(jme, 4 * (h * 8 + n), 64);
      yb8[n] = x[(size_t)j * DIN + lane];
    }
#pragma unroll
    for (int n = 0; n < 8; ++n) yb8[n] *= xb;
#pragma unroll
    for (int s = 1; s < 64; s <<= 1) {
#pragma unroll
      for (int n = 0; n < 8; ++n) yb8[n] += __shfl_xor(yb8[n], s, 64);
    }
#pragma unroll
    for (int n = 0; n < 8; ++n) xyv[h * 8 + n] = yb8[n];
  }
  float xy = xyv[0];
#pragma unroll
  for (int n = 1; n < NEI; ++n) xy = (nn == n) ? xyv[n] : xy;

  // gate math, ONCE per (n,k) pair (lane-parallel)
  const float Bc = 1.f - x2;
  const float A = 1.f - 2.f * xy + y2me;
  const float den = fmaxf(1.f - 2.f * xy + x2 * y2me, 1e-15f);
  const float inv = 1.f / den;
  const float num2 = fmaxf(A * A * x2 - 2.f * A * Bc * xy + Bc * Bc * y2me, 0.f);
  const float nm2 = num2 * inv * inv;
  const float nmr = sqrtf(fmaxf(nm2, 1e-14f));
  const float scl = (nmr > 0.99999f) ? (0.99999f / nmr) : 1.f;
  const float fac = inv * scl;
  const float n02 = nm2 * scl * scl;
  const float B2 = 1.f - n02;
  const float dd = fac * (Bc * Pjme - A * Pbme);  // x0 . x_kernel[k]
  const float xk2 = sXK2[kme];
  const float A2 = 1.f - 2.f * dd + xk2;
  const float dn2 = fmaxf(1.f - 2.f * dd + n02 * xk2, 1e-15f);
  const float nu2 = fmaxf(A2 * A2 * n02 - 2.f * A2 * B2 * dd + B2 * B2 * xk2, 0.f);
  const float mm2 = nu2 / (dn2 * dn2);
  float w = 0.f;
  if (mm2 < 0.101505f && mskme > 0.f) {  // tanh(0.33)^2 gate
    const float dis = 2.f * artanh_c(sqrtf(fmaxf(mm2, 1e-14f)));
    w = fmaxf(1.f - dis * (1.0f / 0.66f), 0.f) * mskme;
  }
  const unsigned long long act = __ballot(w > 0.f);
  if (act == 0ull) {  // common case: nothing active -> zero output
    out[(size_t)b * DOUT + lane] = 0.f;
    return;
  }

  // rare path: full per-(k,n) pipeline, vector over lane=d
  float midv[KK];
#pragma unroll
  for (int k = 0; k < KK; ++k) {
    float macc = 0.f, wsm = 0.f;
    unsigned long long m = act & (0x1111111111111111ull << k);
    const float ebt = sEB[k][lane];
    const float eb2 = sEB2[k];
    while (m) {
      const int g = __ffsll(m) - 1;
      m &= m - 1;
      const float wn = __shfl(w, g, 64);
      const float fac_n = __shfl(fac, g, 64);
      const float A_n = __shfl(A, g, 64);
      const float n02_n = __shfl(n02, g, 64);
      const int j_n = __shfl(jme, g, 64);
      const float yd = x[(size_t)j_n * DIN + lane];
      const float x0t = fac_n * (Bc * yd - A_n * xb);
      const float n0 = sqrtf(fmaxf(n02_n, 1e-14f));
      const float al = artanh_c(n0) / n0;
      asm volatile("s_waitcnt lgkmcnt(0)" ::: "memory");
      sUv[wv][lane] = al * x0t;  // u = logmap0(x0)
      asm volatile("s_waitcnt lgkmcnt(0)" ::: "memory");
      __builtin_amdgcn_sched_barrier(0);
      // h_pre[o=lane] = sum_d W[k][o][d] * u[d]; W from global (L2-hot), u broadcast from LDS
      float a0 = 0.f, a1 = 0.f, a2 = 0.f, a3 = 0.f;
      const float4* wrow = reinterpret_cast<const float4*>(Wg) + ((k * DOUT + lane) << 4);
      const float4* urow = reinterpret_cast<const float4*>(&sUv[wv][0]);
#pragma unroll
      for (int g4 = 0; g4 < 16; ++g4) {
        const float4 w4 = wrow[g4];
        const float4 u4 = urow[g4];
        a0 = fmaf(w4.x, u4.x, a0);
        a1 = fmaf(w4.y, u4.y, a1);
        a2 = fmaf(w4.z, u4.z, a2);
        a3 = fmaf(w4.w, u4.w, a3);
      }
      const float hpre = (a0 + a1) + (a2 + a3);
      const float nh2 = wave_bcast_sum(hpre * hpre);
      const float nh = sqrtf(fmaxf(nh2, 1e-14f));
      const float sh = tanhf(nh) / nh;
      const float ht = sh * hpre;              // h = expmap0(h_pre)
      const float hx2 = sh * sh * nh2;
      const float hxy = wave_bcast_sum(ht * ebt);
      const float A3 = 1.f + 2.f * hxy + eb2;  // proj(mobius_add(h, eb))
      const float B3 = 1.f - hx2;
      const float dn3 = fmaxf(1.f + 2.f * hxy + hx2 * eb2, 1e-15f);
      float hm = (A3 * ht + B3 * ebt) / dn3;
      float n2h = wave_bcast_sum(hm * hm);
      const float nnh = sqrtf(fmaxf(n2h, 1e-14f));
      if (nnh > 0.99999f) {
        const float s = 0.99999f / nnh;
        hm *= s;
        n2h *= s * s;
      }
      const float ip = 1.f / (1.f + n2h);      // kx = p2k(hm), gamma
      const float kx = 2.f * hm * ip;
      const float kx2 = 4.f * n2h * ip * ip;
      const float gam = 1.f / sqrtf(fmaxf(1.f - kx2, 1e-7f));
      const float wgv = wn * gam;
      macc = fmaf(wgv, kx, macc);
      wsm += wgv;
    }
    midv[k] = macc / fmaxf(wsm, 1e-10f);
  }

  float m2v[KK];
#pragma unroll
  for (int k = 0; k < KK; ++k) m2v[k] = midv[k] * midv[k];
#pragma unroll
  for (int s = 1; s < 64; s <<= 1) {
#pragma unroll
    for (int k = 0; k < KK; ++k) m2v[k] += __shfl_xor(m2v[k], s, 64);
  }
  float onum = 0.f, oden = 0.f;
#pragma unroll
  for (int k = 0; k < KK; ++k) {
    const float g = 1.f / sqrtf(fmaxf(1.f - m2v[k], 1e-7f));
    onum = fmaf(g, midv[k], onum);
    oden += g;
  }
  const float ok = onum / fmaxf(oden, 1e-10f);
  const float no2 = wave_bcast_sum(ok * ok);
  float p = ok / (1.f + sqrtf(fmaxf(1.f - no2, 1e-7f)));
  float np2 = wave_bcast_sum(p * p);
  float npn = sqrtf(fmaxf(np2, 1e-14f));
  if (npn > 0.99999f) {
    p *= 0.99999f / npn;
    npn = 0.99999f;
  }
  const float al2 = artanh_c(npn) / npn;
  const float rr = fmaxf(al2 * p, 0.f);
  const float nr2 = wave_bcast_sum(rr * rr);
  const float nrr = sqrtf(fmaxf(nr2, 1e-14f));
  out[(size_t)b * DOUT + lane] = tanhf(nrr) / nrr * rr;
}

// ---------------- fallback (round-1 kernel, no-workspace path) ----------------
__global__ __launch_bounds__(512) void kpa_main_fb(
    const float* __restrict__ x, const int* __restrict__ nei,
    const float* __restrict__ nmask, const float* __restrict__ Wg,
    const float* __restrict__ bias, const float* __restrict__ kt,
    float* __restrict__ out, int npts) {
  __shared__ __align__(16) float sW[KK * DOUT * DIN];
  __shared__ __align__(16) float sU[8][NEI][DIN];
  __shared__ float sXK[KK][DIN];
  __shared__ float sEB[KK][DOUT];
  __shared__ float sXK2[KK], sEB2[KK];
  __shared__ float sWgt[8][KK][NEI];
  __shared__ int sAny;

  const int tid = threadIdx.x, wv = tid >> 6, lane = tid & 63;
  if (tid == 0) sAny = 0;
  if (wv < KK) {
    float v = kt[wv * DIN + lane];
    float n2 = wave_bcast_sum(v * v);
    float nr = sqrtf(fmaxf(n2, 1e-14f));
    float xkv = tanhf(nr) / nr * v;
    sXK[wv][lane] = xkv;
    float s2 = wave_bcast_sum(xkv * xkv);
    if (lane == 0) sXK2[wv] = s2;
  } else {
    const int k = wv - KK;
    float v = bias[k * DOUT + lane];
    float n2 = wave_bcast_sum(v * v);
    float nr = sqrtf(fmaxf(n2, 1e-14f));
    float ebv = tanhf(nr) / nr * v;
    sEB[k][lane] = ebv;
    float s2 = wave_bcast_sum(ebv * ebv);
    if (lane == 0) sEB2[k] = s2;
  }
  __syncthreads();

  const int b = blockIdx.x * 8 + wv;
  const bool alive = b < npts;
  unsigned actK[KK] = {0u, 0u, 0u, 0u};

  if (alive) {
    const float xb = x[(size_t)b * DIN + lane];
    float x2 = wave_bcast_sum(xb * xb);
    float Pb[KK];
#pragma unroll
    for (int k = 0; k < KK; ++k) Pb[k] = wave_bcast_sum(xb * sXK[k][lane]);

    int jn = 0;
    float mkv = 0.f;
    if (lane < NEI) {
      jn = nei[b * NEI + lane];
      mkv = nmask[b * NEI + lane];
    }
    int ji[NEI];
#pragma unroll
    for (int n = 0; n < NEI; ++n) ji[n] = __shfl(jn, n, 64);
    float yv[NEI];
#pragma unroll
    for (int n = 0; n < NEI; ++n) yv[n] = x[(size_t)ji[n] * DIN + lane];
    float xyv[NEI];
#pragma unroll
    for (int n = 0; n < NEI; ++n) xyv[n] = xb * yv[n];
#pragma unroll
    for (int s = 1; s < 64; s <<= 1) {
#pragma unroll
      for (int n = 0; n < NEI; ++n) xyv[n] += __shfl_xor(xyv[n], s, 64);
    }
    float y2v[NEI];
#pragma unroll
    for (int n = 0; n < NEI; ++n) y2v[n] = yv[n] * yv[n];
#pragma unroll
    for (int s = 1; s < 64; s <<= 1) {
#pragma unroll
      for (int n = 0; n < NEI; ++n) y2v[n] += __shfl_xor(y2v[n], s, 64);
    }

    const float B = 1.f - x2;
#pragma unroll 1
    for (int n = 0; n < NEI; ++n) {
      const float xy = xyv[n];
      const float msk = __shfl(mkv, n, 64);
      const float y2 = y2v[n];
      const float A = 1.f - 2.f * xy + y2;
      const float den = fmaxf(1.f - 2.f * xy + x2 * y2, 1e-15f);
      const float inv = 1.f / den;
      const float num2 = fmaxf(A * A * x2 - 2.f * A * B * xy + B * B * y2, 0.f);
      const float nm2 = num2 * inv * inv;
      const float nmr = sqrtf(fmaxf(nm2, 1e-14f));
      const float scl = (nmr > 0.99999f) ? (0.99999f / nmr) : 1.f;
      const float fac = inv * scl;
      const float n02 = nm2 * scl * scl;
      const float B2 = 1.f - n02;
      const float x0t = fac * (B * yv[n] - A * xb);
      bool anyact = false;
#pragma unroll
      for (int k = 0; k < KK; ++k) {
        const float d = wave_bcast_sum(x0t * sXK[k][lane]);
        const float xk2 = sXK2[k];
        const float A2 = 1.f - 2.f * d + xk2;
        const float dn2 = fmaxf(1.f - 2.f * d + n02 * xk2, 1e-15f);
        const float nu2 = fmaxf(A2 * A2 * n02 - 2.f * A2 * B2 * d + B2 * B2 * xk2, 0.f);
        const float mm2 = nu2 / (dn2 * dn2);
        float w = 0.f;
        if (mm2 < 0.101505f && msk > 0.f) {
          const float dis = 2.f * artanh_c(sqrtf(fmaxf(mm2, 1e-14f)));
          w = fmaxf(1.f - dis * (1.f / 0.66f), 0.f) * msk;
        }
        if (lane == 0) sWgt[wv][k][n] = w;
        if (w > 0.f) { actK[k] |= (1u << n); anyact = true; }
      }
      if (anyact) {
        const float n0 = sqrtf(fmaxf(n02, 1e-14f));
        const float al = artanh_c(n0) / n0;
        sU[wv][n][lane] = al * x0t;
      }
    }
    if (lane == 0 && (actK[0] | actK[1] | actK[2] | actK[3])) sAny = 1;
  }

  __syncthreads();
  if (sAny) {
    const float4* Wv = reinterpret_cast<const float4*>(Wg);
    float4* Ws = reinterpret_cast<float4*>(sW);
#pragma unroll
    for (int it = 0; it < (KK * DOUT * 16) / 512; ++it) {
      const int c = it * 512 + tid;
      const float4 v = Wv[c];
      const int g = c & 15, ko = c >> 4, o = ko & 63;
      Ws[(ko << 4) + (g ^ (o & 15))] = v;
    }
  }
  __syncthreads();
  if (!alive) return;

  float midv[KK];
  const int sw = lane & 15;
#pragma unroll 1
  for (int k = 0; k < KK; ++k) {
    float macc = 0.f, wsm = 0.f;
    unsigned act = actK[k];
    const float ebt = sEB[k][lane];
    const float eb2 = sEB2[k];
    const float4* wrow = reinterpret_cast<const float4*>(sW) + ((k * DOUT + lane) << 4);
    while (act) {
      const int n = __ffs(act) - 1;
      act &= act - 1;
      const float w = sWgt[wv][k][n];
      const float4* urow = reinterpret_cast<const float4*>(&sU[wv][n][0]);
      float a0 = 0.f, a1 = 0.f, a2 = 0.f, a3 = 0.f;
#pragma unroll
      for (int g = 0; g < 16; ++g) {
        const float4 w4 = wrow[g ^ sw];
        const float4 u4 = urow[g];
        a0 = fmaf(w4.x, u4.x, a0);
        a1 = fmaf(w4.y, u4.y, a1);
        a2 = fmaf(w4.z, u4.z, a2);
        a3 = fmaf(w4.w, u4.w, a3);
      }
      const float hpre = (a0 + a1) + (a2 + a3);
      const float nh2 = wave_bcast_sum(hpre * hpre);
      const float nh = sqrtf(fmaxf(nh2, 1e-14f));
      const float sh = tanhf(nh) / nh;
      const float ht = sh * hpre;
      const float hx2 = sh * sh * nh2;
      const float hxy = wave_bcast_sum(ht * ebt);
      const float A3 = 1.f + 2.f * hxy + eb2;
      const float B3 = 1.f - hx2;
      const float dn3 = fmaxf(1.f + 2.f * hxy + hx2 * eb2, 1e-15f);
      float hm = (A3 * ht + B3 * ebt) / dn3;
      float n2h = wave_bcast_sum(hm * hm);
      const float nnh = sqrtf(fmaxf(n2h, 1e-14f));
      if (nnh > 0.99999f) {
        const float s = 0.99999f / nnh;
        hm *= s;
        n2h *= s * s;
      }
      const float ip = 1.f / (1.f + n2h);
      const float kx = 2.f * hm * ip;
      const float kx2 = 4.f * n2h * ip * ip;
      const float gam = 1.f / sqrtf(fmaxf(1.f - kx2, 1e-7f));
      const float wgv = w * gam;
      macc = fmaf(wgv, kx, macc);
      wsm += wgv;
    }
    midv[k] = macc / fmaxf(wsm, 1e-10f);
  }

  float m2v[KK];
#pragma unroll
  for (int k = 0; k < KK; ++k) m2v[k] = midv[k] * midv[k];
#pragma unroll
  for (int s = 1; s < 64; s <<= 1) {
#pragma unroll
    for (int k = 0; k < KK; ++k) m2v[k] += __shfl_xor(m2v[k], s, 64);
  }
  float onum = 0.f, oden = 0.f;
#pragma unroll
  for (int k = 0; k < KK; ++k) {
    const float g = 1.f / sqrtf(fmaxf(1.f - m2v[k], 1e-7f));
    onum = fmaf(g, midv[k], onum);
    oden += g;
  }
  const float ok = onum / fmaxf(oden, 1e-10f);
  const float no2 = wave_bcast_sum(ok * ok);
  float p = ok / (1.f + sqrtf(fmaxf(1.f - no2, 1e-7f)));
  float np2 = wave_bcast_sum(p * p);
  float npn = sqrtf(fmaxf(np2, 1e-14f));
  if (npn > 0.99999f) {
    p *= 0.99999f / npn;
    npn = 0.99999f;
  }
  const float al = artanh_c(npn) / npn;
  const float r = fmaxf(al * p, 0.f);
  const float nr2 = wave_bcast_sum(r * r);
  const float nr = sqrtf(fmaxf(nr2, 1e-14f));
  out[(size_t)b * DOUT + lane] = tanhf(nr) / nr * r;
}

extern "C" void kernel_launch(void* const* d_in, const int* in_sizes, int n_in,
                              void* d_out, int out_size, void* d_ws, size_t ws_size,
                              hipStream_t stream) {
  const float* x = (const float*)d_in[0];
  const int* nei = (const int*)d_in[1];
  const float* nmask = (const float*)d_in[2];
  const float* W = (const float*)d_in[3];
  const float* bias = (const float*)d_in[4];
  const float* kt = (const float*)d_in[5];
  float* out = (float*)d_out;

  const int npts = in_sizes[0] / DIN;
  const size_t need = (size_t)npts * (KK + 1) * sizeof(float);

  if (d_ws != nullptr && ws_size >= need) {
    float4* P = (float4*)d_ws;
    float* Q = (float*)((char*)d_ws + (size_t)npts * KK * sizeof(float));
    const int grid = (npts + WPB - 1) / WPB;
    kpa_pre<<<grid, BLK, 0, stream>>>(x, kt, P, Q, npts);
    kpa_main2<<<grid, BLK, 0, stream>>>(x, nei, nmask, W, bias, kt, P, Q, out, npts);
  } else {
    const int grid = (npts + 7) / 8;
    kpa_main_fb<<<grid, 512, 0, stream>>>(x, nei, nmask, W, bias, kt, out, npts);
  }
}

// Round 3
// 30.329 us; speedup vs baseline: 7.5532x; 1.6182x over previous
//
#include <hip/hip_runtime.h>

#define NEI 16
#define KK 4
#define DIN 64
#define DOUT 64
#define WPB 4
#define BLK (WPB * 64)

__device__ __forceinline__ float wave_bcast_sum(float v) {
#pragma unroll
  for (int s = 1; s < 64; s <<= 1) v += __shfl_xor(v, s, 64);
  return v;
}

__device__ __forceinline__ float artanh_c(float z) {
  z = fminf(z, 1.0f - 1e-7f);
  z = fmaxf(z, -1.0f + 1e-7f);
  return atanhf(z);
}

// One fused kernel: one wave per point.
// Dot phase:  lane = (n = lane>>2, q = lane&3), 16 dims per lane, quad-reduce.
// Gate phase: lane = (n = lane>>2, k = lane&3)  -- same quad grouping, no remap.
__global__ __launch_bounds__(BLK) void kpa_fused(
    const float* __restrict__ x, const int* __restrict__ nei,
    const float* __restrict__ nmask, const float* __restrict__ Wg,
    const float* __restrict__ bias, const float* __restrict__ kt,
    float* __restrict__ out, int npts) {
  __shared__ __align__(16) float sXK[KK][DIN];
  __shared__ __align__(16) float sEB[KK][DOUT];
  __shared__ float sXK2[KK], sEB2[KK];
  __shared__ __align__(16) float sUv[WPB][DIN];

  const int tid = threadIdx.x, wv = tid >> 6, lane = tid & 63;

  // stage x_kernel[wv] = expmap0(kt[wv]) and eb[wv] = expmap0(bias[wv])  (WPB==KK)
  {
    float v = kt[wv * DIN + lane];
    float bv = bias[wv * DOUT + lane];
    float n2 = wave_bcast_sum(v * v);
    float nr = sqrtf(fmaxf(n2, 1e-14f));
    float t = tanhf(nr);
    sXK[wv][lane] = t / nr * v;
    float bn2 = wave_bcast_sum(bv * bv);
    float bnr = sqrtf(fmaxf(bn2, 1e-14f));
    float tb = tanhf(bnr);
    sEB[wv][lane] = tb / bnr * bv;
    if (lane == 0) {
      sXK2[wv] = t * t;  // |expmap0(kt)|^2 = tanh(|kt|)^2
      sEB2[wv] = tb * tb;
    }
  }
  __syncthreads();

  const int b = blockIdx.x * WPB + wv;
  if (b >= npts) return;

  const int nn = lane >> 2, q = lane & 3, kme = lane & 3;
  const int jme = nei[b * NEI + nn];
  const float mskme = nmask[b * NEI + nn];

  // 16 dims per lane: y chunk of neighbor nn, x_b chunk
  float4 y4[4], xb4[4];
  {
    const float4* yrow = reinterpret_cast<const float4*>(x + (size_t)jme * DIN + q * 16);
    const float4* xrow = reinterpret_cast<const float4*>(x + (size_t)b * DIN + q * 16);
#pragma unroll
    for (int c = 0; c < 4; ++c) {
      y4[c] = yrow[c];
      xb4[c] = xrow[c];
    }
  }

  // local partial dots over the 16 dims
  float xy = 0.f, y2 = 0.f, x2 = 0.f;
  float dk[KK] = {0.f, 0.f, 0.f, 0.f};  // y . xk[k]
  float pk[KK] = {0.f, 0.f, 0.f, 0.f};  // xb . xk[k]
#pragma unroll
  for (int c = 0; c < 4; ++c) {
    xy = fmaf(y4[c].x, xb4[c].x, xy); xy = fmaf(y4[c].y, xb4[c].y, xy);
    xy = fmaf(y4[c].z, xb4[c].z, xy); xy = fmaf(y4[c].w, xb4[c].w, xy);
    y2 = fmaf(y4[c].x, y4[c].x, y2); y2 = fmaf(y4[c].y, y4[c].y, y2);
    y2 = fmaf(y4[c].z, y4[c].z, y2); y2 = fmaf(y4[c].w, y4[c].w, y2);
    x2 = fmaf(xb4[c].x, xb4[c].x, x2); x2 = fmaf(xb4[c].y, xb4[c].y, x2);
    x2 = fmaf(xb4[c].z, xb4[c].z, x2); x2 = fmaf(xb4[c].w, xb4[c].w, x2);
  }
#pragma unroll
  for (int k = 0; k < KK; ++k) {
    const float4* xkp = reinterpret_cast<const float4*>(&sXK[k][q * 16]);
#pragma unroll
    for (int c = 0; c < 4; ++c) {
      const float4 xk4 = xkp[c];
      dk[k] = fmaf(y4[c].x, xk4.x, dk[k]); dk[k] = fmaf(y4[c].y, xk4.y, dk[k]);
      dk[k] = fmaf(y4[c].z, xk4.z, dk[k]); dk[k] = fmaf(y4[c].w, xk4.w, dk[k]);
      pk[k] = fmaf(xb4[c].x, xk4.x, pk[k]); pk[k] = fmaf(xb4[c].y, xk4.y, pk[k]);
      pk[k] = fmaf(xb4[c].z, xk4.z, pk[k]); pk[k] = fmaf(xb4[c].w, xk4.w, pk[k]);
    }
  }
  // quad reduction: sum over q (lanes n*4..n*4+3); all 11 values land in every quad lane
#pragma unroll
  for (int s = 1; s < 4; s <<= 1) {
    xy += __shfl_xor(xy, s, 64);
    y2 += __shfl_xor(y2, s, 64);
    x2 += __shfl_xor(x2, s, 64);
#pragma unroll
    for (int k = 0; k < KK; ++k) {
      dk[k] += __shfl_xor(dk[k], s, 64);
      pk[k] += __shfl_xor(pk[k], s, 64);
    }
  }
  const float y2me = y2;
  const float Pjme = dk[kme];
  const float Pbme = pk[kme];

  // gate math, once per (n,k) pair
  const float Bc = 1.f - x2;
  const float A = 1.f - 2.f * xy + y2me;
  const float den = fmaxf(1.f - 2.f * xy + x2 * y2me, 1e-15f);
  const float inv = 1.f / den;
  const float num2 = fmaxf(A * A * x2 - 2.f * A * Bc * xy + Bc * Bc * y2me, 0.f);
  const float nm2 = num2 * inv * inv;
  const float nmr = sqrtf(fmaxf(nm2, 1e-14f));
  const float scl = (nmr > 0.99999f) ? (0.99999f / nmr) : 1.f;
  const float fac = inv * scl;
  const float n02 = nm2 * scl * scl;
  const float B2 = 1.f - n02;
  const float dd = fac * (Bc * Pjme - A * Pbme);  // x0 . x_kernel[k]
  const float xk2 = sXK2[kme];
  const float A2 = 1.f - 2.f * dd + xk2;
  const float dn2 = fmaxf(1.f - 2.f * dd + n02 * xk2, 1e-15f);
  const float nu2 = fmaxf(A2 * A2 * n02 - 2.f * A2 * B2 * dd + B2 * B2 * xk2, 0.f);
  const float mm2 = nu2 / (dn2 * dn2);
  float w = 0.f;
  if (mm2 < 0.101505f && mskme > 0.f) {  // tanh(0.33)^2 gate
    const float dis = 2.f * artanh_c(sqrtf(fmaxf(mm2, 1e-14f)));
    w = fmaxf(1.f - dis * (1.0f / 0.66f), 0.f) * mskme;
  }
  const unsigned long long act = __ballot(w > 0.f);
  if (act == 0ull) {  // common case: nothing active -> zero output
    out[(size_t)b * DOUT + lane] = 0.f;
    return;
  }

  // rare path: full per-(k,n) pipeline, vector over lane=d
  const float xbd = x[(size_t)b * DIN + lane];
  float midv[KK];
#pragma unroll
  for (int k = 0; k < KK; ++k) {
    float macc = 0.f, wsm = 0.f;
    unsigned long long m = act & (0x1111111111111111ull << k);
    const float ebt = sEB[k][lane];
    const float eb2 = sEB2[k];
    while (m) {
      const int g = __ffsll(m) - 1;
      m &= m - 1;
      const float wn = __shfl(w, g, 64);
      const float fac_n = __shfl(fac, g, 64);
      const float A_n = __shfl(A, g, 64);
      const float n02_n = __shfl(n02, g, 64);
      const int j_n = __shfl(jme, g, 64);
      const float yd = x[(size_t)j_n * DIN + lane];
      const float x0t = fac_n * (Bc * yd - A_n * xbd);
      const float n0 = sqrtf(fmaxf(n02_n, 1e-14f));
      const float al = artanh_c(n0) / n0;
      asm volatile("s_waitcnt lgkmcnt(0)" ::: "memory");
      sUv[wv][lane] = al * x0t;  // u = logmap0(x0)
      asm volatile("s_waitcnt lgkmcnt(0)" ::: "memory");
      __builtin_amdgcn_sched_barrier(0);
      // h_pre[o=lane] = sum_d W[k][o][d] * u[d]; W from global (L2-hot), u broadcast from LDS
      float a0 = 0.f, a1 = 0.f, a2 = 0.f, a3 = 0.f;
      const float4* wrow = reinterpret_cast<const float4*>(Wg) + ((k * DOUT + lane) << 4);
      const float4* urow = reinterpret_cast<const float4*>(&sUv[wv][0]);
#pragma unroll
      for (int g4 = 0; g4 < 16; ++g4) {
        const float4 w4 = wrow[g4];
        const float4 u4 = urow[g4];
        a0 = fmaf(w4.x, u4.x, a0);
        a1 = fmaf(w4.y, u4.y, a1);
        a2 = fmaf(w4.z, u4.z, a2);
        a3 = fmaf(w4.w, u4.w, a3);
      }
      const float hpre = (a0 + a1) + (a2 + a3);
      const float nh2 = wave_bcast_sum(hpre * hpre);
      const float nh = sqrtf(fmaxf(nh2, 1e-14f));
      const float sh = tanhf(nh) / nh;
      const float ht = sh * hpre;              // h = expmap0(h_pre)
      const float hx2 = sh * sh * nh2;
      const float hxy = wave_bcast_sum(ht * ebt);
      const float A3 = 1.f + 2.f * hxy + eb2;  // proj(mobius_add(h, eb))
      const float B3 = 1.f - hx2;
      const float dn3 = fmaxf(1.f + 2.f * hxy + hx2 * eb2, 1e-15f);
      float hm = (A3 * ht + B3 * ebt) / dn3;
      float n2h = wave_bcast_sum(hm * hm);
      const float nnh = sqrtf(fmaxf(n2h, 1e-14f));
      if (nnh > 0.99999f) {
        const float s = 0.99999f / nnh;
        hm *= s;
        n2h *= s * s;
      }
      const float ip = 1.f / (1.f + n2h);      // kx = p2k(hm), gamma
      const float kx = 2.f * hm * ip;
      const float kx2 = 4.f * n2h * ip * ip;
      const float gam = 1.f / sqrtf(fmaxf(1.f - kx2, 1e-7f));
      const float wgv = wn * gam;
      macc = fmaf(wgv, kx, macc);
      wsm += wgv;
    }
    midv[k] = macc / fmaxf(wsm, 1e-10f);
  }

  float m2v[KK];
#pragma unroll
  for (int k = 0; k < KK; ++k) m2v[k] = midv[k] * midv[k];
#pragma unroll
  for (int s = 1; s < 64; s <<= 1) {
#pragma unroll
    for (int k = 0; k < KK; ++k) m2v[k] += __shfl_xor(m2v[k], s, 64);
  }
  float onum = 0.f, oden = 0.f;
#pragma unroll
  for (int k = 0; k < KK; ++k) {
    const float g = 1.f / sqrtf(fmaxf(1.f - m2v[k], 1e-7f));
    onum = fmaf(g, midv[k], onum);
    oden += g;
  }
  const float ok = onum / fmaxf(oden, 1e-10f);
  const float no2 = wave_bcast_sum(ok * ok);
  float p = ok / (1.f + sqrtf(fmaxf(1.f - no2, 1e-7f)));
  float np2 = wave_bcast_sum(p * p);
  float npn = sqrtf(fmaxf(np2, 1e-14f));
  if (npn > 0.99999f) {
    p *= 0.99999f / npn;
    npn = 0.99999f;
  }
  const float al2 = artanh_c(npn) / npn;
  const float rr = fmaxf(al2 * p, 0.f);
  const float nr2 = wave_bcast_sum(rr * rr);
  const float nrr = sqrtf(fmaxf(nr2, 1e-14f));
  out[(size_t)b * DOUT + lane] = tanhf(nrr) / nrr * rr;
}

extern "C" void kernel_launch(void* const* d_in, const int* in_sizes, int n_in,
                              void* d_out, int out_size, void* d_ws, size_t ws_size,
                              hipStream_t stream) {
  const float* x = (const float*)d_in[0];
  const int* nei = (const int*)d_in[1];
  const float* nmask = (const float*)d_in[2];
  const float* W = (const float*)d_in[3];
  const float* bias = (const float*)d_in[4];
  const float* kt = (const float*)d_in[5];
  float* out = (float*)d_out;

  const int npts = in_sizes[0] / DIN;
  const int grid = (npts + WPB - 1) / WPB;
  kpa_fused<<<grid, BLK, 0, stream>>>(x, nei, nmask, W, bias, kt, out, npts);
}

// Round 4
// 24.203 us; speedup vs baseline: 9.4652x; 1.2531x over previous
//
#include <hip/hip_runtime.h>

#define NEI 16
#define KK 4
#define DIN 64
#define DOUT 64
#define WPB 4
#define BLK (WPB * 64)

__device__ __forceinline__ float wave_bcast_sum(float v) {
#pragma unroll
  for (int s = 1; s < 64; s <<= 1) v += __shfl_xor(v, s, 64);
  return v;
}

__device__ __forceinline__ float artanh_c(float z) {
  z = fminf(z, 1.0f - 1e-7f);
  z = fmaxf(z, -1.0f + 1e-7f);
  return atanhf(z);
}

// fast tanh for r >= 0 (v_exp_f32 based, ~1e-7 rel err)
__device__ __forceinline__ float tanh_fast(float r) {
  const float e = __expf(2.f * r);
  return (e - 1.f) / (e + 1.f);
}

// One fused kernel: one wave per point.
// Dot phase:  lane = (n = lane>>2, q = lane&3), 16 dims per lane, quad-reduce.
// Pregate:    hyperbolic triangle inequality on |mobius(-x,y)|^2 only.
// Rare path:  exact gate + full per-(k,n) pipeline (identical math to round 3).
__global__ __launch_bounds__(BLK) void kpa_fused(
    const float* __restrict__ x, const int* __restrict__ nei,
    const float* __restrict__ nmask, const float* __restrict__ Wg,
    const float* __restrict__ bias, const float* __restrict__ kt,
    float* __restrict__ out, int npts) {
  __shared__ __align__(16) float sXK[KK][DIN];
  __shared__ __align__(16) float sEB[KK][DOUT];
  __shared__ float sXK2[KK], sEB2[KK], sAT[KK];
  __shared__ __align__(16) float sUv[WPB][DIN];

  const int tid = threadIdx.x, wv = tid >> 6, lane = tid & 63;

  // stage x_kernel[wv] = expmap0(kt[wv]), eb[wv] = expmap0(bias[wv])  (WPB==KK)
  {
    float v = kt[wv * DIN + lane];
    float bv = bias[wv * DOUT + lane];
    float n2 = wave_bcast_sum(v * v);
    float nr = sqrtf(fmaxf(n2, 1e-14f));
    float t = tanh_fast(nr);
    sXK[wv][lane] = t / nr * v;
    float bn2 = wave_bcast_sum(bv * bv);
    float bnr = sqrtf(fmaxf(bn2, 1e-14f));
    float tb = tanh_fast(bnr);
    sEB[wv][lane] = tb / bnr * bv;
    if (lane == 0) {
      sXK2[wv] = t * t;  // |expmap0(kt)|^2 = tanh(|kt|)^2
      sEB2[wv] = tb * tb;
      sAT[wv] = nr;      // artanh(|x_kernel|) = |kt| exactly
    }
  }
  __syncthreads();

  const int b = blockIdx.x * WPB + wv;
  if (b >= npts) return;

  // pregate threshold: n0 must satisfy artanh(n0) < 0.33 + max_k artanh|xk|
  const float maxAT = fmaxf(fmaxf(sAT[0], sAT[1]), fmaxf(sAT[2], sAT[3]));
  const float thr = tanh_fast(0.34f + maxAT);  // +0.01 fp-safety margin
  const float thr2 = thr * thr;

  const int nn = lane >> 2, q = lane & 3, kme = lane & 3;
  const int jme = nei[b * NEI + nn];

  // 16 dims per lane: y chunk of neighbor nn, x_b chunk
  float4 y4[4], xb4[4];
  {
    const float4* yrow = reinterpret_cast<const float4*>(x + (size_t)jme * DIN + q * 16);
    const float4* xrow = reinterpret_cast<const float4*>(x + (size_t)b * DIN + q * 16);
#pragma unroll
    for (int c = 0; c < 4; ++c) {
      xb4[c] = xrow[c];
      y4[c] = yrow[c];
    }
  }

  // local partial dots (3 values only for the pregate)
  float xy = 0.f, y2 = 0.f, x2 = 0.f;
#pragma unroll
  for (int c = 0; c < 4; ++c) {
    xy = fmaf(y4[c].x, xb4[c].x, xy); xy = fmaf(y4[c].y, xb4[c].y, xy);
    xy = fmaf(y4[c].z, xb4[c].z, xy); xy = fmaf(y4[c].w, xb4[c].w, xy);
    y2 = fmaf(y4[c].x, y4[c].x, y2); y2 = fmaf(y4[c].y, y4[c].y, y2);
    y2 = fmaf(y4[c].z, y4[c].z, y2); y2 = fmaf(y4[c].w, y4[c].w, y2);
    x2 = fmaf(xb4[c].x, xb4[c].x, x2); x2 = fmaf(xb4[c].y, xb4[c].y, x2);
    x2 = fmaf(xb4[c].z, xb4[c].z, x2); x2 = fmaf(xb4[c].w, xb4[c].w, x2);
  }
#pragma unroll
  for (int s = 1; s < 4; s <<= 1) {
    xy += __shfl_xor(xy, s, 64);
    y2 += __shfl_xor(y2, s, 64);
    x2 += __shfl_xor(x2, s, 64);
  }

  // nm2 = |mobius_add(-x, y)|^2 (pre-proj); proj only shrinks, so filter is safe
  const float Bc = 1.f - x2;
  const float A = 1.f - 2.f * xy + y2;
  const float den = fmaxf(1.f - 2.f * xy + x2 * y2, 1e-15f);
  const float inv = 1.f / den;
  const float num2 = fmaxf(A * A * x2 - 2.f * A * Bc * xy + Bc * Bc * y2, 0.f);
  const float nm2 = num2 * inv * inv;

  if (__ballot(nm2 < thr2) == 0ull) {  // common case: every neighbor hyperbolically far
    out[(size_t)b * DOUT + lane] = 0.f;
    return;
  }

  // ---- rare path: exact gate ----
  const float mskme = nmask[b * NEI + nn];
  float dk[KK] = {0.f, 0.f, 0.f, 0.f};  // y . xk[k]
  float pk[KK] = {0.f, 0.f, 0.f, 0.f};  // xb . xk[k]
#pragma unroll
  for (int k = 0; k < KK; ++k) {
    const float4* xkp = reinterpret_cast<const float4*>(&sXK[k][q * 16]);
#pragma unroll
    for (int c = 0; c < 4; ++c) {
      const float4 xk4 = xkp[c];
      dk[k] = fmaf(y4[c].x, xk4.x, dk[k]); dk[k] = fmaf(y4[c].y, xk4.y, dk[k]);
      dk[k] = fmaf(y4[c].z, xk4.z, dk[k]); dk[k] = fmaf(y4[c].w, xk4.w, dk[k]);
      pk[k] = fmaf(xb4[c].x, xk4.x, pk[k]); pk[k] = fmaf(xb4[c].y, xk4.y, pk[k]);
      pk[k] = fmaf(xb4[c].z, xk4.z, pk[k]); pk[k] = fmaf(xb4[c].w, xk4.w, pk[k]);
    }
  }
#pragma unroll
  for (int s = 1; s < 4; s <<= 1) {
#pragma unroll
    for (int k = 0; k < KK; ++k) {
      dk[k] += __shfl_xor(dk[k], s, 64);
      pk[k] += __shfl_xor(pk[k], s, 64);
    }
  }
  const float Pjme = dk[kme];
  const float Pbme = pk[kme];

  const float nmr = sqrtf(fmaxf(nm2, 1e-14f));
  const float scl = (nmr > 0.99999f) ? (0.99999f / nmr) : 1.f;
  const float fac = inv * scl;
  const float n02 = nm2 * scl * scl;
  const float B2 = 1.f - n02;
  const float dd = fac * (Bc * Pjme - A * Pbme);  // x0 . x_kernel[k]
  const float xk2 = sXK2[kme];
  const float A2 = 1.f - 2.f * dd + xk2;
  const float dn2 = fmaxf(1.f - 2.f * dd + n02 * xk2, 1e-15f);
  const float nu2 = fmaxf(A2 * A2 * n02 - 2.f * A2 * B2 * dd + B2 * B2 * xk2, 0.f);
  const float mm2 = nu2 / (dn2 * dn2);
  float w = 0.f;
  if (mm2 < 0.101505f && mskme > 0.f) {  // tanh(0.33)^2 gate
    const float dis = 2.f * artanh_c(sqrtf(fmaxf(mm2, 1e-14f)));
    w = fmaxf(1.f - dis * (1.0f / 0.66f), 0.f) * mskme;
  }
  const unsigned long long act = __ballot(w > 0.f);
  if (act == 0ull) {
    out[(size_t)b * DOUT + lane] = 0.f;
    return;
  }

  // full per-(k,n) pipeline, vector over lane=d
  const float xbd = x[(size_t)b * DIN + lane];
  float midv[KK];
#pragma unroll
  for (int k = 0; k < KK; ++k) {
    float macc = 0.f, wsm = 0.f;
    unsigned long long m = act & (0x1111111111111111ull << k);
    const float ebt = sEB[k][lane];
    const float eb2 = sEB2[k];
    while (m) {
      const int g = __ffsll(m) - 1;
      m &= m - 1;
      const float wn = __shfl(w, g, 64);
      const float fac_n = __shfl(fac, g, 64);
      const float A_n = __shfl(A, g, 64);
      const float n02_n = __shfl(n02, g, 64);
      const int j_n = __shfl(jme, g, 64);
      const float yd = x[(size_t)j_n * DIN + lane];
      const float x0t = fac_n * (Bc * yd - A_n * xbd);
      const float n0 = sqrtf(fmaxf(n02_n, 1e-14f));
      const float al = artanh_c(n0) / n0;
      asm volatile("s_waitcnt lgkmcnt(0)" ::: "memory");
      sUv[wv][lane] = al * x0t;  // u = logmap0(x0)
      asm volatile("s_waitcnt lgkmcnt(0)" ::: "memory");
      __builtin_amdgcn_sched_barrier(0);
      // h_pre[o=lane] = sum_d W[k][o][d] * u[d]; W from global (L2-hot)
      float a0 = 0.f, a1 = 0.f, a2 = 0.f, a3 = 0.f;
      const float4* wrow = reinterpret_cast<const float4*>(Wg) + ((k * DOUT + lane) << 4);
      const float4* urow = reinterpret_cast<const float4*>(&sUv[wv][0]);
#pragma unroll
      for (int g4 = 0; g4 < 16; ++g4) {
        const float4 w4 = wrow[g4];
        const float4 u4 = urow[g4];
        a0 = fmaf(w4.x, u4.x, a0);
        a1 = fmaf(w4.y, u4.y, a1);
        a2 = fmaf(w4.z, u4.z, a2);
        a3 = fmaf(w4.w, u4.w, a3);
      }
      const float hpre = (a0 + a1) + (a2 + a3);
      const float nh2 = wave_bcast_sum(hpre * hpre);
      const float nh = sqrtf(fmaxf(nh2, 1e-14f));
      const float sh = tanhf(nh) / nh;
      const float ht = sh * hpre;              // h = expmap0(h_pre)
      const float hx2 = sh * sh * nh2;
      const float hxy = wave_bcast_sum(ht * ebt);
      const float A3 = 1.f + 2.f * hxy + eb2;  // proj(mobius_add(h, eb))
      const float B3 = 1.f - hx2;
      const float dn3 = fmaxf(1.f + 2.f * hxy + hx2 * eb2, 1e-15f);
      float hm = (A3 * ht + B3 * ebt) / dn3;
      float n2h = wave_bcast_sum(hm * hm);
      const float nnh = sqrtf(fmaxf(n2h, 1e-14f));
      if (nnh > 0.99999f) {
        const float s = 0.99999f / nnh;
        hm *= s;
        n2h *= s * s;
      }
      const float ip = 1.f / (1.f + n2h);      // kx = p2k(hm), gamma
      const float kx = 2.f * hm * ip;
      const float kx2 = 4.f * n2h * ip * ip;
      const float gam = 1.f / sqrtf(fmaxf(1.f - kx2, 1e-7f));
      const float wgv = wn * gam;
      macc = fmaf(wgv, kx, macc);
      wsm += wgv;
    }
    midv[k] = macc / fmaxf(wsm, 1e-10f);
  }

  float m2v[KK];
#pragma unroll
  for (int k = 0; k < KK; ++k) m2v[k] = midv[k] * midv[k];
#pragma unroll
  for (int s = 1; s < 64; s <<= 1) {
#pragma unroll
    for (int k = 0; k < KK; ++k) m2v[k] += __shfl_xor(m2v[k], s, 64);
  }
  float onum = 0.f, oden = 0.f;
#pragma unroll
  for (int k = 0; k < KK; ++k) {
    const float g = 1.f / sqrtf(fmaxf(1.f - m2v[k], 1e-7f));
    onum = fmaf(g, midv[k], onum);
    oden += g;
  }
  const float ok = onum / fmaxf(oden, 1e-10f);
  const float no2 = wave_bcast_sum(ok * ok);
  float p = ok / (1.f + sqrtf(fmaxf(1.f - no2, 1e-7f)));
  float np2 = wave_bcast_sum(p * p);
  float npn = sqrtf(fmaxf(np2, 1e-14f));
  if (npn > 0.99999f) {
    p *= 0.99999f / npn;
    npn = 0.99999f;
  }
  const float al2 = artanh_c(npn) / npn;
  const float rr = fmaxf(al2 * p, 0.f);
  const float nr2 = wave_bcast_sum(rr * rr);
  const float nrr = sqrtf(fmaxf(nr2, 1e-14f));
  out[(size_t)b * DOUT + lane] = tanhf(nrr) / nrr * rr;
}

extern "C" void kernel_launch(void* const* d_in, const int* in_sizes, int n_in,
                              void* d_out, int out_size, void* d_ws, size_t ws_size,
                              hipStream_t stream) {
  const float* x = (const float*)d_in[0];
  const int* nei = (const int*)d_in[1];
  const float* nmask = (const float*)d_in[2];
  const float* W = (const float*)d_in[3];
  const float* bias = (const float*)d_in[4];
  const float* kt = (const float*)d_in[5];
  float* out = (float*)d_out;

  const int npts = in_sizes[0] / DIN;
  const int grid = (npts + WPB - 1) / WPB;
  kpa_fused<<<grid, BLK, 0, stream>>>(x, nei, nmask, W, bias, kt, out, npts);
}

// Round 5
// 23.966 us; speedup vs baseline: 9.5589x; 1.0099x over previous
//
#include <hip/hip_runtime.h>

#define NEI 16
#define KK 4
#define DIN 64
#define DOUT 64
#define WPB 4
#define BLK (WPB * 64)
#define MAXBLOCKS 1280

__device__ __forceinline__ float wave_bcast_sum(float v) {
#pragma unroll
  for (int s = 1; s < 64; s <<= 1) v += __shfl_xor(v, s, 64);
  return v;
}

__device__ __forceinline__ float artanh_c(float z) {
  z = fminf(z, 1.0f - 1e-7f);
  z = fmaxf(z, -1.0f + 1e-7f);
  return atanhf(z);
}

// fast tanh for r >= 0 (v_exp_f32 based, ~1e-7 rel err)
__device__ __forceinline__ float tanh_fast(float r) {
  const float e = __expf(2.f * r);
  return (e - 1.f) / (e + 1.f);
}

// Persistent-block fused kernel: each wave grid-strides over points.
// Dot phase:  lane = (n = lane>>2, q = lane&3), 16 dims per lane, quad-reduce.
// Pregate:    hyperbolic triangle inequality on |mobius(-x,y)|^2 only.
// Rare path:  exact gate + full per-(k,n) pipeline (identical math to round 4).
__global__ __launch_bounds__(BLK) void kpa_fused(
    const float* __restrict__ x, const int* __restrict__ nei,
    const float* __restrict__ nmask, const float* __restrict__ Wg,
    const float* __restrict__ bias, const float* __restrict__ kt,
    float* __restrict__ out, int npts) {
  __shared__ __align__(16) float sXK[KK][DIN];
  __shared__ __align__(16) float sEB[KK][DOUT];
  __shared__ float sXK2[KK], sEB2[KK], sAT[KK];
  __shared__ __align__(16) float sUv[WPB][DIN];

  const int tid = threadIdx.x, wv = tid >> 6, lane = tid & 63;

  // stage x_kernel[wv] = expmap0(kt[wv]), eb[wv] = expmap0(bias[wv])  (WPB==KK)
  {
    float v = kt[wv * DIN + lane];
    float bv = bias[wv * DOUT + lane];
    float n2 = wave_bcast_sum(v * v);
    float nr = sqrtf(fmaxf(n2, 1e-14f));
    float t = tanh_fast(nr);
    sXK[wv][lane] = t / nr * v;
    float bn2 = wave_bcast_sum(bv * bv);
    float bnr = sqrtf(fmaxf(bn2, 1e-14f));
    float tb = tanh_fast(bnr);
    sEB[wv][lane] = tb / bnr * bv;
    if (lane == 0) {
      sXK2[wv] = t * t;  // |expmap0(kt)|^2 = tanh(|kt|)^2
      sEB2[wv] = tb * tb;
      sAT[wv] = nr;      // artanh(|x_kernel|) = |kt| exactly
    }
  }
  __syncthreads();

  // pregate threshold: n0 must satisfy artanh(n0) < 0.33 + max_k artanh|xk|
  const float maxAT = fmaxf(fmaxf(sAT[0], sAT[1]), fmaxf(sAT[2], sAT[3]));
  const float thr = tanh_fast(0.34f + maxAT);  // +0.01 fp-safety margin
  const float thr2 = thr * thr;

  const int nn = lane >> 2, q = lane & 3, kme = lane & 3;
  const int stride = gridDim.x * WPB;

  for (int b = blockIdx.x * WPB + wv; b < npts; b += stride) {
    const int jme = nei[b * NEI + nn];

    // 16 dims per lane: y chunk of neighbor nn, x_b chunk
    float4 y4[4], xb4[4];
    {
      const float4* yrow = reinterpret_cast<const float4*>(x + (size_t)jme * DIN + q * 16);
      const float4* xrow = reinterpret_cast<const float4*>(x + (size_t)b * DIN + q * 16);
#pragma unroll
      for (int c = 0; c < 4; ++c) {
        xb4[c] = xrow[c];
        y4[c] = yrow[c];
      }
    }

    // local partial dots (3 values only for the pregate)
    float xy = 0.f, y2 = 0.f, x2 = 0.f;
#pragma unroll
    for (int c = 0; c < 4; ++c) {
      xy = fmaf(y4[c].x, xb4[c].x, xy); xy = fmaf(y4[c].y, xb4[c].y, xy);
      xy = fmaf(y4[c].z, xb4[c].z, xy); xy = fmaf(y4[c].w, xb4[c].w, xy);
      y2 = fmaf(y4[c].x, y4[c].x, y2); y2 = fmaf(y4[c].y, y4[c].y, y2);
      y2 = fmaf(y4[c].z, y4[c].z, y2); y2 = fmaf(y4[c].w, y4[c].w, y2);
      x2 = fmaf(xb4[c].x, xb4[c].x, x2); x2 = fmaf(xb4[c].y, xb4[c].y, x2);
      x2 = fmaf(xb4[c].z, xb4[c].z, x2); x2 = fmaf(xb4[c].w, xb4[c].w, x2);
    }
#pragma unroll
    for (int s = 1; s < 4; s <<= 1) {
      xy += __shfl_xor(xy, s, 64);
      y2 += __shfl_xor(y2, s, 64);
      x2 += __shfl_xor(x2, s, 64);
    }

    // nm2 = |mobius_add(-x, y)|^2 (pre-proj); proj only shrinks, so filter is safe
    const float Bc = 1.f - x2;
    const float A = 1.f - 2.f * xy + y2;
    const float den = fmaxf(1.f - 2.f * xy + x2 * y2, 1e-15f);
    const float inv = 1.f / den;
    const float num2 = fmaxf(A * A * x2 - 2.f * A * Bc * xy + Bc * Bc * y2, 0.f);
    const float nm2 = num2 * inv * inv;

    if (__ballot(nm2 < thr2) == 0ull) {  // common case: all neighbors hyperbolically far
      out[(size_t)b * DOUT + lane] = 0.f;
      continue;
    }

    // ---- rare path: exact gate ----
    const float mskme = nmask[b * NEI + nn];
    float dk[KK] = {0.f, 0.f, 0.f, 0.f};  // y . xk[k]
    float pk[KK] = {0.f, 0.f, 0.f, 0.f};  // xb . xk[k]
#pragma unroll
    for (int k = 0; k < KK; ++k) {
      const float4* xkp = reinterpret_cast<const float4*>(&sXK[k][q * 16]);
#pragma unroll
      for (int c = 0; c < 4; ++c) {
        const float4 xk4 = xkp[c];
        dk[k] = fmaf(y4[c].x, xk4.x, dk[k]); dk[k] = fmaf(y4[c].y, xk4.y, dk[k]);
        dk[k] = fmaf(y4[c].z, xk4.z, dk[k]); dk[k] = fmaf(y4[c].w, xk4.w, dk[k]);
        pk[k] = fmaf(xb4[c].x, xk4.x, pk[k]); pk[k] = fmaf(xb4[c].y, xk4.y, pk[k]);
        pk[k] = fmaf(xb4[c].z, xk4.z, pk[k]); pk[k] = fmaf(xb4[c].w, xk4.w, pk[k]);
      }
    }
#pragma unroll
    for (int s = 1; s < 4; s <<= 1) {
#pragma unroll
      for (int k = 0; k < KK; ++k) {
        dk[k] += __shfl_xor(dk[k], s, 64);
        pk[k] += __shfl_xor(pk[k], s, 64);
      }
    }
    const float Pjme = dk[kme];
    const float Pbme = pk[kme];

    const float nmr = sqrtf(fmaxf(nm2, 1e-14f));
    const float scl = (nmr > 0.99999f) ? (0.99999f / nmr) : 1.f;
    const float fac = inv * scl;
    const float n02 = nm2 * scl * scl;
    const float B2 = 1.f - n02;
    const float dd = fac * (Bc * Pjme - A * Pbme);  // x0 . x_kernel[k]
    const float xk2 = sXK2[kme];
    const float A2 = 1.f - 2.f * dd + xk2;
    const float dn2 = fmaxf(1.f - 2.f * dd + n02 * xk2, 1e-15f);
    const float nu2 = fmaxf(A2 * A2 * n02 - 2.f * A2 * B2 * dd + B2 * B2 * xk2, 0.f);
    const float mm2 = nu2 / (dn2 * dn2);
    float w = 0.f;
    if (mm2 < 0.101505f && mskme > 0.f) {  // tanh(0.33)^2 gate
      const float dis = 2.f * artanh_c(sqrtf(fmaxf(mm2, 1e-14f)));
      w = fmaxf(1.f - dis * (1.0f / 0.66f), 0.f) * mskme;
    }
    const unsigned long long act = __ballot(w > 0.f);
    if (act == 0ull) {
      out[(size_t)b * DOUT + lane] = 0.f;
      continue;
    }

    // full per-(k,n) pipeline, vector over lane=d
    const float xbd = x[(size_t)b * DIN + lane];
    float midv[KK];
#pragma unroll
    for (int k = 0; k < KK; ++k) {
      float macc = 0.f, wsm = 0.f;
      unsigned long long m = act & (0x1111111111111111ull << k);
      const float ebt = sEB[k][lane];
      const float eb2 = sEB2[k];
      while (m) {
        const int g = __ffsll(m) - 1;
        m &= m - 1;
        const float wn = __shfl(w, g, 64);
        const float fac_n = __shfl(fac, g, 64);
        const float A_n = __shfl(A, g, 64);
        const float n02_n = __shfl(n02, g, 64);
        const int j_n = __shfl(jme, g, 64);
        const float yd = x[(size_t)j_n * DIN + lane];
        const float x0t = fac_n * (Bc * yd - A_n * xbd);
        const float n0 = sqrtf(fmaxf(n02_n, 1e-14f));
        const float al = artanh_c(n0) / n0;
        asm volatile("s_waitcnt lgkmcnt(0)" ::: "memory");
        sUv[wv][lane] = al * x0t;  // u = logmap0(x0)
        asm volatile("s_waitcnt lgkmcnt(0)" ::: "memory");
        __builtin_amdgcn_sched_barrier(0);
        // h_pre[o=lane] = sum_d W[k][o][d] * u[d]; W from global (L2-hot)
        float a0 = 0.f, a1 = 0.f, a2 = 0.f, a3 = 0.f;
        const float4* wrow = reinterpret_cast<const float4*>(Wg) + ((k * DOUT + lane) << 4);
        const float4* urow = reinterpret_cast<const float4*>(&sUv[wv][0]);
#pragma unroll
        for (int g4 = 0; g4 < 16; ++g4) {
          const float4 w4 = wrow[g4];
          const float4 u4 = urow[g4];
          a0 = fmaf(w4.x, u4.x, a0);
          a1 = fmaf(w4.y, u4.y, a1);
          a2 = fmaf(w4.z, u4.z, a2);
          a3 = fmaf(w4.w, u4.w, a3);
        }
        const float hpre = (a0 + a1) + (a2 + a3);
        const float nh2 = wave_bcast_sum(hpre * hpre);
        const float nh = sqrtf(fmaxf(nh2, 1e-14f));
        const float sh = tanhf(nh) / nh;
        const float ht = sh * hpre;              // h = expmap0(h_pre)
        const float hx2 = sh * sh * nh2;
        const float hxy = wave_bcast_sum(ht * ebt);
        const float A3 = 1.f + 2.f * hxy + eb2;  // proj(mobius_add(h, eb))
        const float B3 = 1.f - hx2;
        const float dn3 = fmaxf(1.f + 2.f * hxy + hx2 * eb2, 1e-15f);
        float hm = (A3 * ht + B3 * ebt) / dn3;
        float n2h = wave_bcast_sum(hm * hm);
        const float nnh = sqrtf(fmaxf(n2h, 1e-14f));
        if (nnh > 0.99999f) {
          const float s = 0.99999f / nnh;
          hm *= s;
          n2h *= s * s;
        }
        const float ip = 1.f / (1.f + n2h);      // kx = p2k(hm), gamma
        const float kx = 2.f * hm * ip;
        const float kx2 = 4.f * n2h * ip * ip;
        const float gam = 1.f / sqrtf(fmaxf(1.f - kx2, 1e-7f));
        const float wgv = wn * gam;
        macc = fmaf(wgv, kx, macc);
        wsm += wgv;
      }
      midv[k] = macc / fmaxf(wsm, 1e-10f);
    }

    float m2v[KK];
#pragma unroll
    for (int k = 0; k < KK; ++k) m2v[k] = midv[k] * midv[k];
#pragma unroll
    for (int s = 1; s < 64; s <<= 1) {
#pragma unroll
      for (int k = 0; k < KK; ++k) m2v[k] += __shfl_xor(m2v[k], s, 64);
    }
    float onum = 0.f, oden = 0.f;
#pragma unroll
    for (int k = 0; k < KK; ++k) {
      const float g = 1.f / sqrtf(fmaxf(1.f - m2v[k], 1e-7f));
      onum = fmaf(g, midv[k], onum);
      oden += g;
    }
    const float ok = onum / fmaxf(oden, 1e-10f);
    const float no2 = wave_bcast_sum(ok * ok);
    float p = ok / (1.f + sqrtf(fmaxf(1.f - no2, 1e-7f)));
    float np2 = wave_bcast_sum(p * p);
    float npn = sqrtf(fmaxf(np2, 1e-14f));
    if (npn > 0.99999f) {
      p *= 0.99999f / npn;
      npn = 0.99999f;
    }
    const float al2 = artanh_c(npn) / npn;
    const float rr = fmaxf(al2 * p, 0.f);
    const float nr2 = wave_bcast_sum(rr * rr);
    const float nrr = sqrtf(fmaxf(nr2, 1e-14f));
    out[(size_t)b * DOUT + lane] = tanhf(nrr) / nrr * rr;
  }
}

extern "C" void kernel_launch(void* const* d_in, const int* in_sizes, int n_in,
                              void* d_out, int out_size, void* d_ws, size_t ws_size,
                              hipStream_t stream) {
  const float* x = (const float*)d_in[0];
  const int* nei = (const int*)d_in[1];
  const float* nmask = (const float*)d_in[2];
  const float* W = (const float*)d_in[3];
  const float* bias = (const float*)d_in[4];
  const float* kt = (const float*)d_in[5];
  float* out = (float*)d_out;

  const int npts = in_sizes[0] / DIN;
  int grid = (npts + WPB - 1) / WPB;
  if (grid > MAXBLOCKS) grid = MAXBLOCKS;
  kpa_fused<<<grid, BLK, 0, stream>>>(x, nei, nmask, W, bias, kt, out, npts);
}